// Round 1
// baseline (698.759 us; speedup 1.0000x reference)
//
#include <hip/hip_runtime.h>
#include <math.h>

#define NA 10000
#define NE 100000
#define PI_F 3.14159265358979323846f

// Row layout of the "uncoupled" per-atom pack: c-blocks of 3^c rows, 32 k each.
// rowOff = {0,1,4,13}, total 40 rows = 1280 floats/atom.
// U concat offsets: U0@0 (1), U1@1 (12), U2@13 (81), U3@94 (432) => 526 floats.

__device__ __forceinline__ void atomAddF(float* p, float v) {
#if defined(__AMDGCN__)
    unsafeAtomicAdd(p, v);
#else
    atomicAdd(p, v);
#endif
}

__device__ __forceinline__ void stage_U(const float* __restrict__ U0,
                                        const float* __restrict__ U1,
                                        const float* __restrict__ U2,
                                        const float* __restrict__ U3,
                                        float* uLds, int t) {
    for (int i = t; i < 526; i += 256) {
        float v;
        if (i == 0)       v = U0[0];
        else if (i < 13)  v = U1[i - 1];
        else if (i < 94)  v = U2[i - 13];
        else              v = U3[i - 94];
        uLds[i] = v;
    }
}

// ---------------- Kernel A: per-atom uncoupled features (unc_f) ----------------
// 8 atoms per 256-block; 32 k-lanes per atom.
__global__ __launch_bounds__(256) void kA_uncf(
    const float* __restrict__ f0, const float* __restrict__ f1,
    const float* __restrict__ f2, const float* __restrict__ f3,
    const float* __restrict__ U0, const float* __restrict__ U1,
    const float* __restrict__ U2, const float* __restrict__ U3,
    float* __restrict__ uncf)
{
    __shared__ float uLds[526];
    const int t = threadIdx.x;
    stage_U(U0, U1, U2, U3, uLds, t);
    __syncthreads();

    const int la = t >> 5, k = t & 31;
    const int a = blockIdx.x * 8 + la;
    float* op = uncf + (size_t)a * 1280;

    // c = 0 (base 96): rows lp=0 only
    {
        float x0 = f0[(size_t)a * 128 + 96 + k];
        op[k] = uLds[0] * x0;
    }
    // c = 1 (base 64)
    {
        float x[4];
        x[0] = f0[(size_t)a * 128 + 64 + k];
#pragma unroll
        for (int m = 0; m < 3; ++m) x[1 + m] = f1[(size_t)a * 288 + m * 96 + 64 + k];
#pragma unroll
        for (int d = 0; d < 3; ++d) {
            float acc = 0.f;
#pragma unroll
            for (int m = 0; m < 4; ++m) acc += uLds[1 + d * 4 + m] * x[m];
            op[(1 + d) * 32 + k] = acc;
        }
    }
    // c = 2 (base 32)
    {
        float x[9];
        x[0] = f0[(size_t)a * 128 + 32 + k];
#pragma unroll
        for (int m = 0; m < 3; ++m) x[1 + m] = f1[(size_t)a * 288 + m * 96 + 32 + k];
#pragma unroll
        for (int m = 0; m < 5; ++m) x[4 + m] = f2[(size_t)a * 320 + m * 64 + 32 + k];
#pragma unroll
        for (int d = 0; d < 9; ++d) {
            float acc = 0.f;
#pragma unroll
            for (int m = 0; m < 9; ++m) acc += uLds[13 + d * 9 + m] * x[m];
            op[(4 + d) * 32 + k] = acc;
        }
    }
    // c = 3 (base 0)
    {
        float x[16];
        x[0] = f0[(size_t)a * 128 + k];
#pragma unroll
        for (int m = 0; m < 3; ++m) x[1 + m] = f1[(size_t)a * 288 + m * 96 + k];
#pragma unroll
        for (int m = 0; m < 5; ++m) x[4 + m] = f2[(size_t)a * 320 + m * 64 + k];
#pragma unroll
        for (int m = 0; m < 7; ++m) x[9 + m] = f3[(size_t)a * 224 + m * 32 + k];
#pragma unroll
        for (int d = 0; d < 27; ++d) {
            float acc = 0.f;
#pragma unroll
            for (int m = 0; m < 16; ++m) acc += uLds[94 + d * 16 + m] * x[m];
            op[(13 + d) * 32 + k] = acc;
        }
    }
}

// ---------------- Kernel B: per-edge message + scatter-add ----------------
// 8 edges per 256-block; 32 k-lanes per edge. 40 atomics/lane.
__global__ __launch_bounds__(256) void kB_edge(
    const float* __restrict__ r,
    const float* __restrict__ sh0, const float* __restrict__ sh1,
    const float* __restrict__ sh2, const float* __restrict__ sh3,
    const float* __restrict__ Wr0, const float* __restrict__ Wr1,
    const float* __restrict__ Wr2, const float* __restrict__ Wr3,
    const float* __restrict__ U0, const float* __restrict__ U1,
    const float* __restrict__ U2, const float* __restrict__ U3,
    const int* __restrict__ centers, const int* __restrict__ neighbors,
    const float* __restrict__ uncf, float* __restrict__ pooled)
{
    __shared__ float uLds[526];
    __shared__ float wLds[2560];      // Wrad0..3 concat: 1024,768,512,256
    __shared__ float shLds[8][16];    // per-edge sh concat in m-order
    const int t = threadIdx.x;
    stage_U(U0, U1, U2, U3, uLds, t);
    for (int i = t; i < 2560; i += 256) {
        float v;
        if (i < 1024)      v = Wr0[i];
        else if (i < 1792) v = Wr1[i - 1024];
        else if (i < 2304) v = Wr2[i - 1792];
        else               v = Wr3[i - 2304];
        wLds[i] = v;
    }
    const int le = t >> 5, k = t & 31;
    const int e = blockIdx.x * 8 + le;
    if (k < 16) {
        float v;
        if (k == 0)      v = sh0[e];
        else if (k < 4)  v = sh1[(size_t)e * 3 + k - 1];
        else if (k < 9)  v = sh2[(size_t)e * 5 + k - 4];
        else             v = sh3[(size_t)e * 7 + k - 9];
        shLds[le][k] = v;
    }
    __syncthreads();

    const float rv = r[e];
    const float fc = 0.5f * (cosf(PI_F * fminf(rv * 0.2f, 1.0f)) + 1.0f);
    const float pref = fc / (rv + 1e-6f);
    const float step = rv * (PI_F * 0.2f);
    float rb[8];
#pragma unroll
    for (int n = 0; n < 8; ++n) rb[n] = sinf((float)(n + 1) * step) * pref;

    const int KL[4] = {128, 96, 64, 32};
    const int WO[4] = {0, 1024, 1792, 2304};
    float rad[4][4];
#pragma unroll
    for (int lp = 0; lp < 4; ++lp) {
#pragma unroll
        for (int c = 0; c < 4; ++c) {
            if (c < lp) continue;
            const int base = 32 * (3 - c);
            float acc = 0.f;
#pragma unroll
            for (int n = 0; n < 8; ++n)
                acc += rb[n] * wLds[WO[lp] + n * KL[lp] + base + k];
            rad[lp][c] = acc;
        }
    }

    const int ctr = centers[e], nbr = neighbors[e];
    const float* uf = uncf + (size_t)nbr * 1280 + k;
    float* pl = pooled + (size_t)ctr * 1280 + k;

    const int UO[4] = {0, 1, 13, 94};
    const int RO[4] = {0, 1, 4, 13};
    const int P3[4] = {1, 3, 9, 27};
#pragma unroll
    for (int c = 0; c < 4; ++c) {
        const int M2 = (c + 1) * (c + 1);
#pragma unroll
        for (int d = 0; d < P3[c]; ++d) {
            float uv = 0.f;
#pragma unroll
            for (int lp = 0; lp <= c; ++lp) {
                float s = 0.f;
#pragma unroll
                for (int ml = 0; ml < 2 * lp + 1; ++ml)
                    s += uLds[UO[c] + d * M2 + lp * lp + ml] * shLds[le][lp * lp + ml];
                uv += s * rad[lp][c];
            }
            const int off = (RO[c] + d) * 32;
            atomAddF(pl + off, uv * uf[off]);
        }
    }
}

// ---------------- Kernel C: couple back + linear + residual ----------------
// 4 atoms per 256-block (Wlin reuse x4).
__global__ __launch_bounds__(256) void kC_out(
    const float* __restrict__ pooled,
    const float* __restrict__ f0, const float* __restrict__ f1,
    const float* __restrict__ f2, const float* __restrict__ f3,
    const float* __restrict__ U0, const float* __restrict__ U1,
    const float* __restrict__ U2, const float* __restrict__ U3,
    const float* __restrict__ W0, const float* __restrict__ W1,
    const float* __restrict__ W2, const float* __restrict__ W3,
    float* __restrict__ out)
{
    __shared__ float uLds[526];
    __shared__ float plds[4 * 1280];
    __shared__ float clds[4 * 960];   // coupled: c-blocks {32,128,288,512} @ {0,32,160,448}
    const int t = threadIdx.x;
    stage_U(U0, U1, U2, U3, uLds, t);
    const int a0 = blockIdx.x * 4;
    for (int i = t; i < 5120; i += 256) plds[i] = pooled[(size_t)a0 * 1280 + i];
    __syncthreads();

    for (int idx = t; idx < 3840; idx += 256) {
        const int la = idx / 960;
        const int rem = idx - la * 960;
        int c, off;
        if (rem < 32)       { c = 0; off = 0; }
        else if (rem < 160) { c = 1; off = 32; }
        else if (rem < 448) { c = 2; off = 160; }
        else                { c = 3; off = 448; }
        const int r2 = rem - off;
        const int m = r2 >> 5, k = r2 & 31;
        const int M2 = (c + 1) * (c + 1);
        const int UOc = (c == 0 ? 0 : c == 1 ? 1 : c == 2 ? 13 : 94);
        const int ROc = (c == 0 ? 0 : c == 1 ? 1 : c == 2 ? 4 : 13);
        const int nd  = (c == 0 ? 1 : c == 1 ? 3 : c == 2 ? 9 : 27);
        float acc = 0.f;
        for (int d = 0; d < nd; ++d)
            acc += uLds[UOc + d * M2 + m] * plds[la * 1280 + (ROc + d) * 32 + k];
        clds[idx] = acc;
    }
    __syncthreads();

    const float* Fp[4] = {f0, f1, f2, f3};
    const float* Wp[4] = {W0, W1, W2, W3};
    const int Kl[4] = {128, 96, 64, 32};
    const int Ml[4] = {1, 3, 5, 7};
    const size_t Ol[4] = {0, 1280000, 4160000, 7360000};
    const int CO[4] = {0, 32, 160, 448};
#pragma unroll
    for (int l = 0; l < 4; ++l) {
        const int K = Kl[l], M = Ml[l], MK = M * K;
        const float* W = Wp[l];
        const float* F = Fp[l];
        for (int idx = t; idx < MK; idx += 256) {
            const int m = idx / K, q = idx - m * K;
            float acc[4];
#pragma unroll
            for (int la = 0; la < 4; ++la)
                acc[la] = F[(size_t)(a0 + la) * MK + idx];
#pragma unroll
            for (int j = 0; j < 4 - l; ++j) {
                const int c = l + j;
                const int cb = CO[c] + (l * l + m) * 32;
#pragma unroll
                for (int k = 0; k < 32; ++k) {
                    const float w = W[(size_t)(32 * j + k) * K + q];
#pragma unroll
                    for (int la = 0; la < 4; ++la)
                        acc[la] += clds[la * 960 + cb + k] * w;
                }
            }
#pragma unroll
            for (int la = 0; la < 4; ++la)
                out[Ol[l] + (size_t)(a0 + la) * MK + idx] = acc[la];
        }
    }
}

extern "C" void kernel_launch(void* const* d_in, const int* in_sizes, int n_in,
                              void* d_out, int out_size, void* d_ws, size_t ws_size,
                              hipStream_t stream)
{
    // Input ordering: setup_inputs() dict order (r, then per-l: sh,feat,Wrad,U,Wlin,
    // then centers,neighbors). Fall back to reference-signature order if sizes say so.
    int ir, ish[4], ift[4], iwr[4], iu[4], iwl[4], ic, in_;
    if (in_sizes[2] == 300000) {
        // signature order: r, sh0..3, feat0..3, Wrad0..3, U0..3, Wlin0..3, centers, neighbors
        ir = 0;
        for (int l = 0; l < 4; ++l) { ish[l] = 1 + l; ift[l] = 5 + l; iwr[l] = 9 + l; iu[l] = 13 + l; iwl[l] = 17 + l; }
        ic = 21; in_ = 22;
    } else {
        ir = 0;
        for (int l = 0; l < 4; ++l) { ish[l] = 1 + 5 * l; ift[l] = 2 + 5 * l; iwr[l] = 3 + 5 * l; iu[l] = 4 + 5 * l; iwl[l] = 5 + 5 * l; }
        ic = 21; in_ = 22;
    }
    const float* r   = (const float*)d_in[ir];
    const float* sh0 = (const float*)d_in[ish[0]];
    const float* sh1 = (const float*)d_in[ish[1]];
    const float* sh2 = (const float*)d_in[ish[2]];
    const float* sh3 = (const float*)d_in[ish[3]];
    const float* f0  = (const float*)d_in[ift[0]];
    const float* f1  = (const float*)d_in[ift[1]];
    const float* f2  = (const float*)d_in[ift[2]];
    const float* f3  = (const float*)d_in[ift[3]];
    const float* Wr0 = (const float*)d_in[iwr[0]];
    const float* Wr1 = (const float*)d_in[iwr[1]];
    const float* Wr2 = (const float*)d_in[iwr[2]];
    const float* Wr3 = (const float*)d_in[iwr[3]];
    const float* U0  = (const float*)d_in[iu[0]];
    const float* U1  = (const float*)d_in[iu[1]];
    const float* U2  = (const float*)d_in[iu[2]];
    const float* U3  = (const float*)d_in[iu[3]];
    const float* Wl0 = (const float*)d_in[iwl[0]];
    const float* Wl1 = (const float*)d_in[iwl[1]];
    const float* Wl2 = (const float*)d_in[iwl[2]];
    const float* Wl3 = (const float*)d_in[iwl[3]];
    const int* centers   = (const int*)d_in[ic];
    const int* neighbors = (const int*)d_in[in_];

    float* uncf   = (float*)d_ws;                      // 10000*1280 f32 = 51.2 MB
    float* pooled = uncf + (size_t)NA * 1280;          // 10000*1280 f32 = 51.2 MB
    float* outp   = (float*)d_out;

    hipMemsetAsync(pooled, 0, (size_t)NA * 1280 * sizeof(float), stream);
    kA_uncf<<<NA / 8, 256, 0, stream>>>(f0, f1, f2, f3, U0, U1, U2, U3, uncf);
    kB_edge<<<NE / 8, 256, 0, stream>>>(r, sh0, sh1, sh2, sh3, Wr0, Wr1, Wr2, Wr3,
                                        U0, U1, U2, U3, centers, neighbors, uncf, pooled);
    kC_out<<<NA / 4, 256, 0, stream>>>(pooled, f0, f1, f2, f3, U0, U1, U2, U3,
                                       Wl0, Wl1, Wl2, Wl3, outp);
}